// Round 10
// baseline (381.307 us; speedup 1.0000x reference)
//
#include <hip/hip_runtime.h>

#define NN 16384   // total nodes (4*64*64)
#define CC 48      // channels
#define SPL 8      // j-stream splits (512 cands/stream, 8 blocks/CU resident)
#define CAPB 16    // per-query pass-2 buffer slots

typedef __attribute__((ext_vector_type(8))) short bf16x8;
typedef __attribute__((ext_vector_type(4))) float f32x4;

__device__ __forceinline__ unsigned short f2bf(float f) {
  unsigned u = __float_as_uint(f);
  unsigned r = ((u >> 16) & 1u) + 0x7fffu;   // RNE
  return (unsigned short)((u + r) >> 16);
}
__device__ __forceinline__ float bf2f(unsigned short h) {
  return __uint_as_float(((unsigned)h) << 16);
}

// ---------- kernel 1: [B,C,H,W] -> xg[N][52] fp32, xh/xl[N][64] bf16 split, sqv[N] ----------
// Also zeroes deg[]; sqv[16383] = +inf (excludes the lone "batch 4" node as a
// candidate for batch-3 queries at zero hot-loop cost: dist = inf, never ranked).
__global__ __launch_bounds__(256) void prep_kernel(const float* __restrict__ x,
                                                   float* __restrict__ xg,
                                                   unsigned short* __restrict__ xh,
                                                   unsigned short* __restrict__ xl,
                                                   float* __restrict__ sqv,
                                                   int* __restrict__ deg) {
  __shared__ float tile[48][65];   // +1 pad
  __shared__ float sqcol[64];
  int tid = threadIdx.x;
  int b   = blockIdx.x >> 6;          // batch image 0..3
  int hw0 = (blockIdx.x & 63) << 6;   // 64-wide hw tile
  if (tid < 64) deg[blockIdx.x * 64 + tid] = 0;
#pragma unroll
  for (int p = 0; p < 12; ++p) {
    int it = tid + p * 256;
    int r = it >> 6, col = it & 63;
    tile[r][col] = x[(b * 48 + r) * 4096 + hw0 + col];
  }
  __syncthreads();
  if (tid < 64) {
    float s = 0.f;
#pragma unroll
    for (int r = 0; r < 48; ++r) { float v = tile[r][tid]; s += v * v; }
    sqcol[tid] = s;
    int node = b * 4096 + hw0 + tid;
    sqv[node] = (node == NN - 1) ? __builtin_inff() : s;
  }
  __syncthreads();
  float4* xg4 = (float4*)xg;
#pragma unroll
  for (int p = 0; p < 4; ++p) {
    int it = tid + p * 256;
    if (it < 832) {
      int col = it / 13;
      int q   = it - col * 13;
      float4 v;
      if (q < 12) {
        v.x = tile[q * 4 + 0][col]; v.y = tile[q * 4 + 1][col];
        v.z = tile[q * 4 + 2][col]; v.w = tile[q * 4 + 3][col];
      } else {
        v.x = sqcol[col]; v.y = 0.f; v.z = 0.f; v.w = 0.f;
      }
      xg4[(b * 4096 + hw0 + col) * 13 + q] = v;
    }
  }
  // bf16 hi/lo split, channels padded 48..63 with zeros
#pragma unroll
  for (int p = 0; p < 16; ++p) {
    int it = tid + p * 256;          // 4096 = 64 nodes x 64 ch
    int col = it >> 6, ch = it & 63;
    float v = (ch < 48) ? tile[ch][col] : 0.f;
    unsigned short h = f2bf(v);
    unsigned short l = f2bf(v - bf2f(h));
    size_t o = (size_t)(b * 4096 + hw0 + col) * 64 + ch;
    xh[o] = h;
    xl[o] = l;
  }
}

// ---------- kernel 2: MFMA distance, two-pass exact top-9 ----------
// A = candidates (streamed), B = queries (resident); lane owns query col,
// sees candidate rows quad*4+reg. dot = hi.hi' + hi.lo' + lo.hi' via 6
// chained mfma_f32_16x16x32_bf16.
// PASS 1 (values only): ONE shared ascending u32 top-9 chain per lane
// (9 regs, not 4x9 — R9's 36-reg version forced AGPR parking / copy tax).
// The 4 candidates/tile insert sequentially. Then per-query quad-merge (LDS)
// -> exact 9th-smallest dist value d9 of this split.
// PASS 2: re-sweep (L1/L2-hot loads, bitwise-identical k32), accept
// k32 <= d9 (exact threshold -> ~9+ties pushes per query per split), push
// (k32<<14|j) u64 to per-query LDS buffer via ds-atomic slot. Owner lanes
// sort <=CAPB entries -> exact top-9 with reference (dist, lower-j) order.
// SPL=8: 512-cand streams, 18 KB LDS -> 8 blocks/CU -> 8 waves/SIMD.
__global__ __launch_bounds__(256, 4) void knn_kernel(const unsigned short* __restrict__ xh,
                                                     const unsigned short* __restrict__ xl,
                                                     const float* __restrict__ sqv,
                                                     unsigned long long* __restrict__ part) {
  __shared__ unsigned int fin[4][64][9];                // 9 KB
  __shared__ unsigned long long pbuf[4][16][CAPB + 1];  // 8.5 KB
  __shared__ int pcnt[4][16];
  int tid = threadIdx.x, wv = tid >> 6, lane = tid & 63;
  int wid = blockIdx.x * 4 + wv;
  int qt = wid & 1023, sp = wid >> 10;        // sp in 0..7
  int col = lane & 15, quad = lane >> 4;
  int batch = qt >> 8;
  int js = batch * 4096 + sp * 512;

  if (lane < 16) pcnt[wv][lane] = 0;

  // resident B-frags (queries)
  int qnode = qt * 16 + col;
  bf16x8 bh0 = *(const bf16x8*)(xh + (size_t)qnode * 64 + quad * 8);
  bf16x8 bh1 = *(const bf16x8*)(xh + (size_t)qnode * 64 + 32 + quad * 8);
  bf16x8 bl0 = *(const bf16x8*)(xl + (size_t)qnode * 64 + quad * 8);
  bf16x8 bl1 = *(const bf16x8*)(xl + (size_t)qnode * 64 + 32 + quad * 8);

  unsigned q9[9];
#pragma unroll
  for (int k = 0; k < 9; ++k) q9[k] = 0xFFFFFFFFu;

  // ---- PASS 1 ----
  {
    const unsigned short* pah = xh + ((size_t)(js + col) * 64 + quad * 8);
    const unsigned short* pal = xl + ((size_t)(js + col) * 64 + quad * 8);
    const float*          psq = sqv + (js + quad * 4);
    bf16x8 nh0 = *(const bf16x8*)(pah);
    bf16x8 nh1 = *(const bf16x8*)(pah + 32);
    bf16x8 nl0 = *(const bf16x8*)(pal);
    bf16x8 nl1 = *(const bf16x8*)(pal + 32);
    float4 nsq = *(const float4*)(psq);
    for (int t = 0; t < 32; ++t) {
      bf16x8 ch0 = nh0, ch1 = nh1, cl0 = nl0, cl1 = nl1;
      float4 csq = nsq;
      int adv = (t < 31) ? 1024 : 0;         // 16 nodes * 64 ch
      pah += adv; pal += adv;
      nh0 = *(const bf16x8*)(pah);
      nh1 = *(const bf16x8*)(pah + 32);
      nl0 = *(const bf16x8*)(pal);
      nl1 = *(const bf16x8*)(pal + 32);
      psq += (t < 31) ? 16 : 0;
      nsq = *(const float4*)(psq);

      f32x4 acc = {0.f, 0.f, 0.f, 0.f};
      acc = __builtin_amdgcn_mfma_f32_16x16x32_bf16(ch0, bh0, acc, 0, 0, 0);
      acc = __builtin_amdgcn_mfma_f32_16x16x32_bf16(ch1, bh1, acc, 0, 0, 0);
      acc = __builtin_amdgcn_mfma_f32_16x16x32_bf16(ch0, bl0, acc, 0, 0, 0);
      acc = __builtin_amdgcn_mfma_f32_16x16x32_bf16(ch1, bl1, acc, 0, 0, 0);
      acc = __builtin_amdgcn_mfma_f32_16x16x32_bf16(cl0, bh0, acc, 0, 0, 0);
      acc = __builtin_amdgcn_mfma_f32_16x16x32_bf16(cl1, bh1, acc, 0, 0, 0);

      float sq4[4] = {csq.x, csq.y, csq.z, csq.w};
#pragma unroll
      for (int reg = 0; reg < 4; ++reg) {
        float dd = fmaf(-2.f, acc[reg], sq4[reg]);   // sq_j - 2 dot (sq_i dropped)
        unsigned u = __float_as_uint(dd);
        unsigned cu = u ^ ((unsigned)((int)u >> 31) | 0x80000000u);  // sortable
#pragma unroll
        for (int kk = 0; kk < 9; ++kk) {
          unsigned mn = min(cu, q9[kk]);
          cu          = max(cu, q9[kk]);
          q9[kk]      = mn;
        }
      }
    }
  }

#pragma unroll
  for (int k = 0; k < 9; ++k) fin[wv][lane][k] = q9[k];
  __syncthreads();

  unsigned d9own = 0xFFFFFFFFu;
  if (lane < 16) {
#pragma unroll
    for (int qd = 1; qd < 4; ++qd) {
      const unsigned* ob = fin[wv][qd * 16 + lane];
      for (int k = 0; k < 9; ++k) {
        unsigned v = ob[k];
        if (v >= q9[8]) break;               // ascending source list
        unsigned cu = v;
#pragma unroll
        for (int kk = 0; kk < 9; ++kk) {
          unsigned mn = min(cu, q9[kk]);
          cu          = max(cu, q9[kk]);
          q9[kk]      = mn;
        }
      }
    }
    d9own = q9[8];                           // exact per-query 9th-smallest (split)
  }
  unsigned d9 = (unsigned)__shfl((int)d9own, col, 64);

  // ---- PASS 2: exact-threshold re-scan, index recovery ----
  {
    const unsigned short* pah = xh + ((size_t)(js + col) * 64 + quad * 8);
    const unsigned short* pal = xl + ((size_t)(js + col) * 64 + quad * 8);
    const float*          psq = sqv + (js + quad * 4);
    bf16x8 nh0 = *(const bf16x8*)(pah);
    bf16x8 nh1 = *(const bf16x8*)(pah + 32);
    bf16x8 nl0 = *(const bf16x8*)(pal);
    bf16x8 nl1 = *(const bf16x8*)(pal + 32);
    float4 nsq = *(const float4*)(psq);
    for (int t = 0; t < 32; ++t) {
      bf16x8 ch0 = nh0, ch1 = nh1, cl0 = nl0, cl1 = nl1;
      float4 csq = nsq;
      int adv = (t < 31) ? 1024 : 0;
      pah += adv; pal += adv;
      nh0 = *(const bf16x8*)(pah);
      nh1 = *(const bf16x8*)(pah + 32);
      nl0 = *(const bf16x8*)(pal);
      nl1 = *(const bf16x8*)(pal + 32);
      psq += (t < 31) ? 16 : 0;
      nsq = *(const float4*)(psq);

      f32x4 acc = {0.f, 0.f, 0.f, 0.f};
      acc = __builtin_amdgcn_mfma_f32_16x16x32_bf16(ch0, bh0, acc, 0, 0, 0);
      acc = __builtin_amdgcn_mfma_f32_16x16x32_bf16(ch1, bh1, acc, 0, 0, 0);
      acc = __builtin_amdgcn_mfma_f32_16x16x32_bf16(ch0, bl0, acc, 0, 0, 0);
      acc = __builtin_amdgcn_mfma_f32_16x16x32_bf16(ch1, bl1, acc, 0, 0, 0);
      acc = __builtin_amdgcn_mfma_f32_16x16x32_bf16(cl0, bh0, acc, 0, 0, 0);
      acc = __builtin_amdgcn_mfma_f32_16x16x32_bf16(cl1, bh1, acc, 0, 0, 0);

      float sq4[4] = {csq.x, csq.y, csq.z, csq.w};
      int jrow = js + t * 16 + quad * 4;
#pragma unroll
      for (int reg = 0; reg < 4; ++reg) {
        float dd = fmaf(-2.f, acc[reg], sq4[reg]);
        unsigned u = __float_as_uint(dd);
        unsigned k32 = u ^ ((unsigned)((int)u >> 31) | 0x80000000u);  // bitwise == pass 1
        if (k32 <= d9) {
          int slot = atomicAdd(&pcnt[wv][col], 1);
          if (slot < CAPB)
            pbuf[wv][col][slot] = ((unsigned long long)k32 << 14) | (unsigned)(jrow + reg);
        }
      }
    }
  }
  __syncthreads();

  if (lane < 16) {
    int n = pcnt[wv][lane];
    n = (n < CAPB) ? n : CAPB;
    unsigned long long q9u[9];
#pragma unroll
    for (int k = 0; k < 9; ++k) q9u[k] = ~0ull;
    for (int m = 0; m < n; ++m) {
      unsigned long long key = pbuf[wv][lane][m];
      if (key < q9u[8]) {
        unsigned long long cu = key;
#pragma unroll
        for (int kk = 0; kk < 9; ++kk) {
          bool lt = cu < q9u[kk];
          unsigned long long mn = lt ? cu : q9u[kk];
          cu      = lt ? q9u[kk] : cu;
          q9u[kk] = mn;
        }
      }
    }
    int i = qt * 16 + lane;
#pragma unroll
    for (int k = 0; k < 9; ++k) part[(size_t)(k * SPL + sp) * NN + i] = q9u[k];
  }
}

// ---------- kernel 3: merge SPL sorted partial lists -> nbr, deg ----------
__global__ __launch_bounds__(64) void merge_kernel(const unsigned long long* __restrict__ part,
                                                   int* __restrict__ nbr,
                                                   int* __restrict__ deg) {
  int i = blockIdx.x * 64 + threadIdx.x;
  unsigned long long q9[9];
#pragma unroll
  for (int k = 0; k < 9; ++k) q9[k] = ~0ull;
  for (int s = 0; s < SPL; ++s) {
    for (int k = 0; k < 9; ++k) {
      unsigned long long key = part[(size_t)(k * SPL + s) * NN + i];
      if (key >= q9[8]) break;   // list k-sorted ascending
      unsigned long long cu = key;
#pragma unroll
      for (int m = 0; m < 9; ++m) {
        bool lt = cu < q9[m];
        unsigned long long mn = lt ? cu : q9[m];
        cu    = lt ? q9[m] : cu;
        q9[m] = mn;
      }
    }
  }
  int outi[9];
#pragma unroll
  for (int k = 0; k < 9; ++k) outi[k] = (int)(q9[k] & 0x3FFFull);
  // node 16383 sits alone in "batch 4": top_k over one valid entry + (-inf) ties
  // -> neighbors {16383, 0,1,...,7} (lowest-index tie-break). Matters for deg[0..7].
  if (i == NN - 1) {
    outi[0] = NN - 1;
#pragma unroll
    for (int k = 1; k < 9; ++k) outi[k] = k - 1;
  }
#pragma unroll
  for (int k = 0; k < 9; ++k) {
    nbr[i * 9 + k] = outi[k];
    atomicAdd(&deg[outi[k]], 1);
  }
}

// ---------- kernel 4: tx1 gather + out = relu(xf@W0 + tx1@W1 + b) ----------
__global__ __launch_bounds__(256) void out_kernel(const float* __restrict__ xg,
                                                  const int* __restrict__ nbr,
                                                  const int* __restrict__ deg,
                                                  const float* __restrict__ W0,
                                                  const float* __restrict__ W1,
                                                  const float* __restrict__ bias,
                                                  float* __restrict__ out) {
  __shared__ float w0s[48 * 48], w1s[48 * 48], bsh[48];
  __shared__ __align__(16) float xr[64 * 48];
  __shared__ float tx[64 * 48];
  __shared__ float wd[64][9];
  __shared__ int   jn[64][9];
  __shared__ float din[64];
  int tid = threadIdx.x;
  int r0  = blockIdx.x * 64;

  for (int p = tid; p < 2304; p += 256) { w0s[p] = W0[p]; w1s[p] = W1[p]; }
  if (tid < 48) bsh[tid] = bias[tid];
  if (tid < 64) {
    int d = deg[r0 + tid];
    din[tid] = d > 0 ? rsqrtf((float)d) : 0.0f;
  }
  const float4* xg4 = (const float4*)xg;
  float4* xr4 = (float4*)xr;
  for (int p = tid; p < 768; p += 256) {
    int r = p / 12, q = p - r * 12;
    xr4[r * 12 + q] = xg4[(r0 + r) * 13 + q];
  }
  for (int p = tid; p < 576; p += 256) {
    int r = p / 9, k = p - r * 9;
    int j = nbr[(r0 + r) * 9 + k];
    jn[r][k] = j;
    int d = deg[j];
    wd[r][k] = d > 0 ? rsqrtf((float)d) : 0.0f;
  }
  __syncthreads();

  for (int p = tid; p < 3072; p += 256) {
    int r = p / 48, ch = p - r * 48;
    float s = 0.f;
#pragma unroll
    for (int k = 0; k < 9; ++k) s += wd[r][k] * xg[jn[r][k] * 52 + ch];
    tx[r * 48 + ch] = -din[r] * s;
  }
  __syncthreads();

  for (int p = tid; p < 3072; p += 256) {
    int r = p / 48, o = p - r * 48;
    float acc = bsh[o];
#pragma unroll
    for (int cc = 0; cc < 48; ++cc)
      acc += xr[r * 48 + cc] * w0s[cc * 48 + o] + tx[r * 48 + cc] * w1s[cc * 48 + o];
    out[(r0 + r) * 48 + o] = fmaxf(acc, 0.f);
  }
}

extern "C" void kernel_launch(void* const* d_in, const int* in_sizes, int n_in,
                              void* d_out, int out_size, void* d_ws, size_t ws_size,
                              hipStream_t stream) {
  const float* x  = (const float*)d_in[0];
  const float* W0 = (const float*)d_in[1];
  const float* W1 = (const float*)d_in[2];
  const float* b  = (const float*)d_in[3];
  float* out = (float*)d_out;
  char* ws = (char*)d_ws;
  float*          xg   = (float*)(ws);                       // 3,407,872 B
  unsigned short* xh   = (unsigned short*)(ws + 3407872);    // 2,097,152 B
  unsigned short* xl   = (unsigned short*)(ws + 5505024);    // 2,097,152 B
  float*          sqv  = (float*)(ws + 7602176);             //    65,536 B
  int*            nbr  = (int*)(ws + 7667712);               //   589,824 B
  int*            deg  = (int*)(ws + 8257536);               //    65,536 B
  unsigned long long* part = (unsigned long long*)(ws + 8323072);  // SPL*9*NN*8 = 9,437,184 B

  prep_kernel<<<256, 256, 0, stream>>>(x, xg, xh, xl, sqv, deg);
  knn_kernel<<<2048, 256, 0, stream>>>(xh, xl, sqv, part);
  merge_kernel<<<256, 64, 0, stream>>>(part, nbr, deg);
  out_kernel<<<256, 256, 0, stream>>>(xg, nbr, deg, W0, W1, b, out);
}

// Round 11
// 245.136 us; speedup vs baseline: 1.5555x; 1.5555x over previous
//
#include <hip/hip_runtime.h>

#define NN 16384   // total nodes (4*64*64)
#define CC 48      // channels
#define SPL 4      // j-stream splits

typedef __attribute__((ext_vector_type(8))) short bf16x8;
typedef __attribute__((ext_vector_type(4))) float f32x4;

__device__ __forceinline__ unsigned short f2bf(float f) {
  unsigned u = __float_as_uint(f);
  unsigned r = ((u >> 16) & 1u) + 0x7fffu;   // RNE
  return (unsigned short)((u + r) >> 16);
}
__device__ __forceinline__ float bf2f(unsigned short h) {
  return __uint_as_float(((unsigned)h) << 16);
}

// ---------- kernel 1: [B,C,H,W] -> xg[N][52] fp32, xh/xl[N][64] bf16 split, sqv[N] ----------
// Also zeroes deg[]; sqv[16383] = +inf (excludes the lone "batch 4" node as a
// candidate for batch-3 queries at zero hot-loop cost: dist = inf, never ranked).
__global__ __launch_bounds__(256) void prep_kernel(const float* __restrict__ x,
                                                   float* __restrict__ xg,
                                                   unsigned short* __restrict__ xh,
                                                   unsigned short* __restrict__ xl,
                                                   float* __restrict__ sqv,
                                                   int* __restrict__ deg) {
  __shared__ float tile[48][65];   // +1 pad
  __shared__ float sqcol[64];
  int tid = threadIdx.x;
  int b   = blockIdx.x >> 6;          // batch image 0..3
  int hw0 = (blockIdx.x & 63) << 6;   // 64-wide hw tile
  if (tid < 64) deg[blockIdx.x * 64 + tid] = 0;
#pragma unroll
  for (int p = 0; p < 12; ++p) {
    int it = tid + p * 256;
    int r = it >> 6, col = it & 63;
    tile[r][col] = x[(b * 48 + r) * 4096 + hw0 + col];
  }
  __syncthreads();
  if (tid < 64) {
    float s = 0.f;
#pragma unroll
    for (int r = 0; r < 48; ++r) { float v = tile[r][tid]; s += v * v; }
    sqcol[tid] = s;
    int node = b * 4096 + hw0 + tid;
    sqv[node] = (node == NN - 1) ? __builtin_inff() : s;
  }
  __syncthreads();
  float4* xg4 = (float4*)xg;
#pragma unroll
  for (int p = 0; p < 4; ++p) {
    int it = tid + p * 256;
    if (it < 832) {
      int col = it / 13;
      int q   = it - col * 13;
      float4 v;
      if (q < 12) {
        v.x = tile[q * 4 + 0][col]; v.y = tile[q * 4 + 1][col];
        v.z = tile[q * 4 + 2][col]; v.w = tile[q * 4 + 3][col];
      } else {
        v.x = sqcol[col]; v.y = 0.f; v.z = 0.f; v.w = 0.f;
      }
      xg4[(b * 4096 + hw0 + col) * 13 + q] = v;
    }
  }
  // bf16 hi/lo split, channels padded 48..63 with zeros
#pragma unroll
  for (int p = 0; p < 16; ++p) {
    int it = tid + p * 256;          // 4096 = 64 nodes x 64 ch
    int col = it >> 6, ch = it & 63;
    float v = (ch < 48) ? tile[ch][col] : 0.f;
    unsigned short h = f2bf(v);
    unsigned short l = f2bf(v - bf2f(h));
    size_t o = (size_t)(b * 4096 + hw0 + col) * 64 + ch;
    xh[o] = h;
    xl[o] = l;
  }
}

// Sorted-insert of key c into ascending 9-list q0..q8, ALL PINNED TO ARCH
// VGPRS via "v" constraints (AGPR would be "a"; R7-R10's allocator kept
// parking the chain in AGPRs, paying v_accvgpr copies every step).
// Alternation: even steps read cur=c write tmp=t, odd steps read t write c —
// 2 inst/step, no moves. Final max (dropped 10th value) lands in t.
#define INS9_F64(c, t, q0, q1, q2, q3, q4, q5, q6, q7, q8)                 \
  asm("v_max_f64 %[vt], %[vc], %[a0]\n\t"                                  \
      "v_min_f64 %[a0], %[vc], %[a0]\n\t"                                  \
      "v_max_f64 %[vc], %[vt], %[a1]\n\t"                                  \
      "v_min_f64 %[a1], %[vt], %[a1]\n\t"                                  \
      "v_max_f64 %[vt], %[vc], %[a2]\n\t"                                  \
      "v_min_f64 %[a2], %[vc], %[a2]\n\t"                                  \
      "v_max_f64 %[vc], %[vt], %[a3]\n\t"                                  \
      "v_min_f64 %[a3], %[vt], %[a3]\n\t"                                  \
      "v_max_f64 %[vt], %[vc], %[a4]\n\t"                                  \
      "v_min_f64 %[a4], %[vc], %[a4]\n\t"                                  \
      "v_max_f64 %[vc], %[vt], %[a5]\n\t"                                  \
      "v_min_f64 %[a5], %[vt], %[a5]\n\t"                                  \
      "v_max_f64 %[vt], %[vc], %[a6]\n\t"                                  \
      "v_min_f64 %[a6], %[vc], %[a6]\n\t"                                  \
      "v_max_f64 %[vc], %[vt], %[a7]\n\t"                                  \
      "v_min_f64 %[a7], %[vt], %[a7]\n\t"                                  \
      "v_max_f64 %[vt], %[vc], %[a8]\n\t"                                  \
      "v_min_f64 %[a8], %[vc], %[a8]\n\t"                                  \
      : [vc] "+v"(c), [vt] "=&v"(t), [a0] "+v"(q0), [a1] "+v"(q1),         \
        [a2] "+v"(q2), [a3] "+v"(q3), [a4] "+v"(q4), [a5] "+v"(q5),        \
        [a6] "+v"(q6), [a7] "+v"(q7), [a8] "+v"(q8))

// ---------- kernel 2: MFMA distance + always-run exact f64 top-9 chain ----------
// Identical structure to the verified R8 kernel (A = candidates streamed,
// B = queries resident; lane owns query col, candidates quad*4+reg; dot =
// hi.hi' + hi.lo' + lo.hi' via 6 chained mfma_f32_16x16x32_bf16; key =
// sortable_u32(dist)*256 + ordinal, exact 40-bit integer in f64, tie-break
// == lower j within a lane). ONLY change: the insert chain is the asm macro
// above, pinning the whole top-9 state in arch VGPRs.
__global__ __launch_bounds__(256, 4) void knn_kernel(const unsigned short* __restrict__ xh,
                                                     const unsigned short* __restrict__ xl,
                                                     const float* __restrict__ sqv,
                                                     unsigned long long* __restrict__ part) {
  __shared__ unsigned long long fin[4][64][9];   // 18.4 KB, final merge only
  int tid = threadIdx.x, wv = tid >> 6, lane = tid & 63;
  int wid = blockIdx.x * 4 + wv;
  int qt = wid & 1023, sp = wid >> 10;
  int col = lane & 15, quad = lane >> 4;
  int batch = qt >> 8;
  int js = batch * 4096 + sp * 1024;

  // resident B-frags (queries)
  int qnode = qt * 16 + col;
  bf16x8 bh0 = *(const bf16x8*)(xh + (size_t)qnode * 64 + quad * 8);
  bf16x8 bh1 = *(const bf16x8*)(xh + (size_t)qnode * 64 + 32 + quad * 8);
  bf16x8 bl0 = *(const bf16x8*)(xl + (size_t)qnode * 64 + quad * 8);
  bf16x8 bl1 = *(const bf16x8*)(xl + (size_t)qnode * 64 + 32 + quad * 8);

  double Q0 = __builtin_inf(), Q1 = Q0, Q2 = Q0, Q3 = Q0, Q4 = Q0,
         Q5 = Q0, Q6 = Q0, Q7 = Q0, Q8 = Q0;

  // prefetch tile 0: A-frags (candidate node js + col) + sq float4
  const unsigned short* pah = xh + ((size_t)(js + col) * 64 + quad * 8);
  const unsigned short* pal = xl + ((size_t)(js + col) * 64 + quad * 8);
  const float*          psq = sqv + (js + quad * 4);
  bf16x8 nh0 = *(const bf16x8*)(pah);
  bf16x8 nh1 = *(const bf16x8*)(pah + 32);
  bf16x8 nl0 = *(const bf16x8*)(pal);
  bf16x8 nl1 = *(const bf16x8*)(pal + 32);
  float4 nsq = *(const float4*)(psq);

  double od = 0.0;   // ordinal base = t*4 (exact integer in f64)
  for (int t = 0; t < 64; ++t) {
    bf16x8 ch0 = nh0, ch1 = nh1, cl0 = nl0, cl1 = nl1;
    float4 csq = nsq;
    int adv = (t < 63) ? 1024 : 0;       // 16 nodes * 64 ch
    pah += adv; pal += adv;
    nh0 = *(const bf16x8*)(pah);
    nh1 = *(const bf16x8*)(pah + 32);
    nl0 = *(const bf16x8*)(pal);
    nl1 = *(const bf16x8*)(pal + 32);
    psq += (t < 63) ? 16 : 0;
    nsq = *(const float4*)(psq);

    f32x4 acc = {0.f, 0.f, 0.f, 0.f};
    acc = __builtin_amdgcn_mfma_f32_16x16x32_bf16(ch0, bh0, acc, 0, 0, 0);  // hi.hi k0-31
    acc = __builtin_amdgcn_mfma_f32_16x16x32_bf16(ch1, bh1, acc, 0, 0, 0);  // hi.hi k32-63
    acc = __builtin_amdgcn_mfma_f32_16x16x32_bf16(ch0, bl0, acc, 0, 0, 0);  // hi.lo
    acc = __builtin_amdgcn_mfma_f32_16x16x32_bf16(ch1, bl1, acc, 0, 0, 0);
    acc = __builtin_amdgcn_mfma_f32_16x16x32_bf16(cl0, bh0, acc, 0, 0, 0);  // lo.hi
    acc = __builtin_amdgcn_mfma_f32_16x16x32_bf16(cl1, bh1, acc, 0, 0, 0);

    float sq4[4] = {csq.x, csq.y, csq.z, csq.w};
#pragma unroll
    for (int reg = 0; reg < 4; ++reg) {
      float d = fmaf(-2.f, acc[reg], sq4[reg]);   // key: sq_j - 2 dot (sq_i dropped)
      unsigned k32 = __float_as_uint(d);
      k32 = ((int)k32 >= 0) ? (k32 | 0x80000000u) : ~k32;   // sortable map
      double key = fma((double)k32, 256.0, od + (double)reg);  // exact 40-bit int
      double tscr;
      INS9_F64(key, tscr, Q0, Q1, Q2, Q3, Q4, Q5, Q6, Q7, Q8);
    }
    od += 4.0;
  }

  // f64 keys -> exact (k32, o) -> j -> packed u64; stage for in-wave quad merge
  double q9d[9] = {Q0, Q1, Q2, Q3, Q4, Q5, Q6, Q7, Q8};
  unsigned long long q9u[9];
#pragma unroll
  for (int k = 0; k < 9; ++k) {
    double d  = q9d[k];
    double hi = floor(d * 0.00390625);     // d * 2^-8, exact
    double lo = d - hi * 256.0;            // ordinal o, exact
    unsigned k32 = (unsigned)hi;
    int o = (int)lo;
    int j = js + (o >> 2) * 16 + quad * 4 + (o & 3);
    q9u[k] = ((unsigned long long)k32 << 14) | (unsigned)j;
    fin[wv][lane][k] = q9u[k];
  }
  __threadfence_block();
  if (lane < 16) {
#pragma unroll
    for (int qd = 1; qd < 4; ++qd) {
      const unsigned long long* ob = fin[wv][qd * 16 + lane];
      for (int k = 0; k < 9; ++k) {
        unsigned long long key = ob[k];
        if (key >= q9u[8]) break;          // sorted ascending
        unsigned long long cu = key;
#pragma unroll
        for (int kk = 0; kk < 9; ++kk) {
          bool lt = cu < q9u[kk];
          unsigned long long mn = lt ? cu : q9u[kk];
          cu      = lt ? q9u[kk] : cu;
          q9u[kk] = mn;
        }
      }
    }
    int i = qt * 16 + lane;
#pragma unroll
    for (int k = 0; k < 9; ++k) part[(size_t)(k * SPL + sp) * NN + i] = q9u[k];
  }
}

// ---------- kernel 3: merge SPL sorted partial lists -> nbr, deg ----------
__global__ __launch_bounds__(64) void merge_kernel(const unsigned long long* __restrict__ part,
                                                   int* __restrict__ nbr,
                                                   int* __restrict__ deg) {
  int i = blockIdx.x * 64 + threadIdx.x;
  unsigned long long q9[9];
#pragma unroll
  for (int k = 0; k < 9; ++k) q9[k] = ~0ull;
  for (int s = 0; s < SPL; ++s) {
    for (int k = 0; k < 9; ++k) {
      unsigned long long key = part[(size_t)(k * SPL + s) * NN + i];
      if (key >= q9[8]) break;   // list k-sorted ascending
      unsigned long long cu = key;
#pragma unroll
      for (int m = 0; m < 9; ++m) {
        bool lt = cu < q9[m];
        unsigned long long mn = lt ? cu : q9[m];
        cu    = lt ? q9[m] : cu;
        q9[m] = mn;
      }
    }
  }
  int outi[9];
#pragma unroll
  for (int k = 0; k < 9; ++k) outi[k] = (int)(q9[k] & 0x3FFFull);
  // node 16383 sits alone in "batch 4": top_k over one valid entry + (-inf) ties
  // -> neighbors {16383, 0,1,...,7} (lowest-index tie-break). Matters for deg[0..7].
  if (i == NN - 1) {
    outi[0] = NN - 1;
#pragma unroll
    for (int k = 1; k < 9; ++k) outi[k] = k - 1;
  }
#pragma unroll
  for (int k = 0; k < 9; ++k) {
    nbr[i * 9 + k] = outi[k];
    atomicAdd(&deg[outi[k]], 1);
  }
}

// ---------- kernel 4: tx1 gather + out = relu(xf@W0 + tx1@W1 + b) ----------
__global__ __launch_bounds__(256) void out_kernel(const float* __restrict__ xg,
                                                  const int* __restrict__ nbr,
                                                  const int* __restrict__ deg,
                                                  const float* __restrict__ W0,
                                                  const float* __restrict__ W1,
                                                  const float* __restrict__ bias,
                                                  float* __restrict__ out) {
  __shared__ float w0s[48 * 48], w1s[48 * 48], bsh[48];
  __shared__ __align__(16) float xr[64 * 48];
  __shared__ float tx[64 * 48];
  __shared__ float wd[64][9];
  __shared__ int   jn[64][9];
  __shared__ float din[64];
  int tid = threadIdx.x;
  int r0  = blockIdx.x * 64;

  for (int p = tid; p < 2304; p += 256) { w0s[p] = W0[p]; w1s[p] = W1[p]; }
  if (tid < 48) bsh[tid] = bias[tid];
  if (tid < 64) {
    int d = deg[r0 + tid];
    din[tid] = d > 0 ? rsqrtf((float)d) : 0.0f;
  }
  const float4* xg4 = (const float4*)xg;
  float4* xr4 = (float4*)xr;
  for (int p = tid; p < 768; p += 256) {
    int r = p / 12, q = p - r * 12;
    xr4[r * 12 + q] = xg4[(r0 + r) * 13 + q];
  }
  for (int p = tid; p < 576; p += 256) {
    int r = p / 9, k = p - r * 9;
    int j = nbr[(r0 + r) * 9 + k];
    jn[r][k] = j;
    int d = deg[j];
    wd[r][k] = d > 0 ? rsqrtf((float)d) : 0.0f;
  }
  __syncthreads();

  for (int p = tid; p < 3072; p += 256) {
    int r = p / 48, ch = p - r * 48;
    float s = 0.f;
#pragma unroll
    for (int k = 0; k < 9; ++k) s += wd[r][k] * xg[jn[r][k] * 52 + ch];
    tx[r * 48 + ch] = -din[r] * s;
  }
  __syncthreads();

  for (int p = tid; p < 3072; p += 256) {
    int r = p / 48, o = p - r * 48;
    float acc = bsh[o];
#pragma unroll
    for (int cc = 0; cc < 48; ++cc)
      acc += xr[r * 48 + cc] * w0s[cc * 48 + o] + tx[r * 48 + cc] * w1s[cc * 48 + o];
    out[(r0 + r) * 48 + o] = fmaxf(acc, 0.f);
  }
}

extern "C" void kernel_launch(void* const* d_in, const int* in_sizes, int n_in,
                              void* d_out, int out_size, void* d_ws, size_t ws_size,
                              hipStream_t stream) {
  const float* x  = (const float*)d_in[0];
  const float* W0 = (const float*)d_in[1];
  const float* W1 = (const float*)d_in[2];
  const float* b  = (const float*)d_in[3];
  float* out = (float*)d_out;
  char* ws = (char*)d_ws;
  float*          xg   = (float*)(ws);                       // 3,407,872 B
  unsigned short* xh   = (unsigned short*)(ws + 3407872);    // 2,097,152 B
  unsigned short* xl   = (unsigned short*)(ws + 5505024);    // 2,097,152 B
  float*          sqv  = (float*)(ws + 7602176);             //    65,536 B
  int*            nbr  = (int*)(ws + 7667712);               //   589,824 B
  int*            deg  = (int*)(ws + 8257536);               //    65,536 B
  unsigned long long* part = (unsigned long long*)(ws + 8323072);  // 4,718,592 B

  prep_kernel<<<256, 256, 0, stream>>>(x, xg, xh, xl, sqv, deg);
  knn_kernel<<<1024, 256, 0, stream>>>(xh, xl, sqv, part);
  merge_kernel<<<256, 64, 0, stream>>>(part, nbr, deg);
  out_kernel<<<256, 256, 0, stream>>>(xg, nbr, deg, W0, W1, b, out);
}

// Round 12
// 244.549 us; speedup vs baseline: 1.5592x; 1.0024x over previous
//
#include <hip/hip_runtime.h>

#define NN 16384   // total nodes (4*64*64)
#define CC 48      // channels
#define SPL 4      // j-stream splits

typedef __attribute__((ext_vector_type(8))) short bf16x8;
typedef __attribute__((ext_vector_type(4))) float f32x4;

__device__ __forceinline__ unsigned short f2bf(float f) {
  unsigned u = __float_as_uint(f);
  unsigned r = ((u >> 16) & 1u) + 0x7fffu;   // RNE
  return (unsigned short)((u + r) >> 16);
}
__device__ __forceinline__ float bf2f(unsigned short h) {
  return __uint_as_float(((unsigned)h) << 16);
}

// Parallel sorted-insert of key c into ascending q[0..8]:
//   q'_0 = min(q0, c); q'_k = max(q_{k-1}, min(q_k, c))   (med3 identity,
// simplified via sortedness q_{k-1} <= q_k). 17 ops, ALL INDEPENDENT —
// dependency depth 2 vs the serial compare-exchange chain's 18 (R8/R11's
// ~450 cyc/tile of exposed dep latency was the stall; issue cost unchanged).
__device__ __forceinline__ void ins9(double c, double q[9]) {
  double m1 = fmin(q[1], c), m2 = fmin(q[2], c), m3 = fmin(q[3], c),
         m4 = fmin(q[4], c), m5 = fmin(q[5], c), m6 = fmin(q[6], c),
         m7 = fmin(q[7], c), m8 = fmin(q[8], c);
  double n0 = fmin(q[0], c);
  double n1 = fmax(q[0], m1), n2 = fmax(q[1], m2), n3 = fmax(q[2], m3),
         n4 = fmax(q[3], m4), n5 = fmax(q[4], m5), n6 = fmax(q[5], m6),
         n7 = fmax(q[6], m7), n8 = fmax(q[7], m8);
  q[0] = n0; q[1] = n1; q[2] = n2; q[3] = n3; q[4] = n4;
  q[5] = n5; q[6] = n6; q[7] = n7; q[8] = n8;
}

// ---------- kernel 1: [B,C,H,W] -> xg[N][52] fp32, xh/xl[N][64] bf16 split, sqv[N] ----------
// Also zeroes deg[]; sqv[16383] = +inf (excludes the lone "batch 4" node as a
// candidate for batch-3 queries at zero hot-loop cost: dist = inf, never ranked).
__global__ __launch_bounds__(256) void prep_kernel(const float* __restrict__ x,
                                                   float* __restrict__ xg,
                                                   unsigned short* __restrict__ xh,
                                                   unsigned short* __restrict__ xl,
                                                   float* __restrict__ sqv,
                                                   int* __restrict__ deg) {
  __shared__ float tile[48][65];   // +1 pad
  __shared__ float sqcol[64];
  int tid = threadIdx.x;
  int b   = blockIdx.x >> 6;          // batch image 0..3
  int hw0 = (blockIdx.x & 63) << 6;   // 64-wide hw tile
  if (tid < 64) deg[blockIdx.x * 64 + tid] = 0;
#pragma unroll
  for (int p = 0; p < 12; ++p) {
    int it = tid + p * 256;
    int r = it >> 6, col = it & 63;
    tile[r][col] = x[(b * 48 + r) * 4096 + hw0 + col];
  }
  __syncthreads();
  if (tid < 64) {
    float s = 0.f;
#pragma unroll
    for (int r = 0; r < 48; ++r) { float v = tile[r][tid]; s += v * v; }
    sqcol[tid] = s;
    int node = b * 4096 + hw0 + tid;
    sqv[node] = (node == NN - 1) ? __builtin_inff() : s;
  }
  __syncthreads();
  float4* xg4 = (float4*)xg;
#pragma unroll
  for (int p = 0; p < 4; ++p) {
    int it = tid + p * 256;
    if (it < 832) {
      int col = it / 13;
      int q   = it - col * 13;
      float4 v;
      if (q < 12) {
        v.x = tile[q * 4 + 0][col]; v.y = tile[q * 4 + 1][col];
        v.z = tile[q * 4 + 2][col]; v.w = tile[q * 4 + 3][col];
      } else {
        v.x = sqcol[col]; v.y = 0.f; v.z = 0.f; v.w = 0.f;
      }
      xg4[(b * 4096 + hw0 + col) * 13 + q] = v;
    }
  }
  // bf16 hi/lo split, channels padded 48..63 with zeros
#pragma unroll
  for (int p = 0; p < 16; ++p) {
    int it = tid + p * 256;          // 4096 = 64 nodes x 64 ch
    int col = it >> 6, ch = it & 63;
    float v = (ch < 48) ? tile[ch][col] : 0.f;
    unsigned short h = f2bf(v);
    unsigned short l = f2bf(v - bf2f(h));
    size_t o = (size_t)(b * 4096 + hw0 + col) * 64 + ch;
    xh[o] = h;
    xl[o] = l;
  }
}

// ---------- kernel 2: MFMA distance + always-run exact f64 top-9 (parallel insert) ----------
// Identical structure/logic to the verified R8/R11 kernel (A = candidates
// streamed, B = queries resident; lane owns query col, candidates quad*4+reg;
// dot = hi.hi' + hi.lo' + lo.hi' via 6 chained mfma_f32_16x16x32_bf16; key =
// sortable_u32(dist)*256 + ordinal, exact 40-bit integer in f64, tie-break
// == lower j within a lane). ONLY change: ins9 parallel insert (dep depth 2).
__global__ __launch_bounds__(256, 4) void knn_kernel(const unsigned short* __restrict__ xh,
                                                     const unsigned short* __restrict__ xl,
                                                     const float* __restrict__ sqv,
                                                     unsigned long long* __restrict__ part) {
  __shared__ unsigned long long fin[4][64][9];   // 18.4 KB, final merge only
  int tid = threadIdx.x, wv = tid >> 6, lane = tid & 63;
  int wid = blockIdx.x * 4 + wv;
  int qt = wid & 1023, sp = wid >> 10;
  int col = lane & 15, quad = lane >> 4;
  int batch = qt >> 8;
  int js = batch * 4096 + sp * 1024;

  // resident B-frags (queries)
  int qnode = qt * 16 + col;
  bf16x8 bh0 = *(const bf16x8*)(xh + (size_t)qnode * 64 + quad * 8);
  bf16x8 bh1 = *(const bf16x8*)(xh + (size_t)qnode * 64 + 32 + quad * 8);
  bf16x8 bl0 = *(const bf16x8*)(xl + (size_t)qnode * 64 + quad * 8);
  bf16x8 bl1 = *(const bf16x8*)(xl + (size_t)qnode * 64 + 32 + quad * 8);

  double q9[9];
#pragma unroll
  for (int k = 0; k < 9; ++k) q9[k] = __builtin_inf();

  // prefetch tile 0: A-frags (candidate node js + col) + sq float4
  const unsigned short* pah = xh + ((size_t)(js + col) * 64 + quad * 8);
  const unsigned short* pal = xl + ((size_t)(js + col) * 64 + quad * 8);
  const float*          psq = sqv + (js + quad * 4);
  bf16x8 nh0 = *(const bf16x8*)(pah);
  bf16x8 nh1 = *(const bf16x8*)(pah + 32);
  bf16x8 nl0 = *(const bf16x8*)(pal);
  bf16x8 nl1 = *(const bf16x8*)(pal + 32);
  float4 nsq = *(const float4*)(psq);

  double od = 0.0;   // ordinal base = t*4 (exact integer in f64)
  for (int t = 0; t < 64; ++t) {
    bf16x8 ch0 = nh0, ch1 = nh1, cl0 = nl0, cl1 = nl1;
    float4 csq = nsq;
    int adv = (t < 63) ? 1024 : 0;       // 16 nodes * 64 ch
    pah += adv; pal += adv;
    nh0 = *(const bf16x8*)(pah);
    nh1 = *(const bf16x8*)(pah + 32);
    nl0 = *(const bf16x8*)(pal);
    nl1 = *(const bf16x8*)(pal + 32);
    psq += (t < 63) ? 16 : 0;
    nsq = *(const float4*)(psq);

    f32x4 acc = {0.f, 0.f, 0.f, 0.f};
    acc = __builtin_amdgcn_mfma_f32_16x16x32_bf16(ch0, bh0, acc, 0, 0, 0);  // hi.hi k0-31
    acc = __builtin_amdgcn_mfma_f32_16x16x32_bf16(ch1, bh1, acc, 0, 0, 0);  // hi.hi k32-63
    acc = __builtin_amdgcn_mfma_f32_16x16x32_bf16(ch0, bl0, acc, 0, 0, 0);  // hi.lo
    acc = __builtin_amdgcn_mfma_f32_16x16x32_bf16(ch1, bl1, acc, 0, 0, 0);
    acc = __builtin_amdgcn_mfma_f32_16x16x32_bf16(cl0, bh0, acc, 0, 0, 0);  // lo.hi
    acc = __builtin_amdgcn_mfma_f32_16x16x32_bf16(cl1, bh1, acc, 0, 0, 0);

    float sq4[4] = {csq.x, csq.y, csq.z, csq.w};
#pragma unroll
    for (int reg = 0; reg < 4; ++reg) {
      float d = fmaf(-2.f, acc[reg], sq4[reg]);   // key: sq_j - 2 dot (sq_i dropped)
      unsigned k32 = __float_as_uint(d);
      k32 = ((int)k32 >= 0) ? (k32 | 0x80000000u) : ~k32;   // sortable map
      double key = fma((double)k32, 256.0, od + (double)reg);  // exact 40-bit int
      ins9(key, q9);
    }
    od += 4.0;
  }

  // f64 keys -> exact (k32, o) -> j -> packed u64; stage for in-wave quad merge
  unsigned long long q9u[9];
#pragma unroll
  for (int k = 0; k < 9; ++k) {
    double d  = q9[k];
    double hi = floor(d * 0.00390625);     // d * 2^-8, exact
    double lo = d - hi * 256.0;            // ordinal o, exact
    unsigned k32 = (unsigned)hi;
    int o = (int)lo;
    int j = js + (o >> 2) * 16 + quad * 4 + (o & 3);
    q9u[k] = ((unsigned long long)k32 << 14) | (unsigned)j;
    fin[wv][lane][k] = q9u[k];
  }
  __threadfence_block();
  if (lane < 16) {
#pragma unroll
    for (int qd = 1; qd < 4; ++qd) {
      const unsigned long long* ob = fin[wv][qd * 16 + lane];
      for (int k = 0; k < 9; ++k) {
        unsigned long long key = ob[k];
        if (key >= q9u[8]) break;          // sorted ascending
        unsigned long long cu = key;
#pragma unroll
        for (int kk = 0; kk < 9; ++kk) {
          bool lt = cu < q9u[kk];
          unsigned long long mn = lt ? cu : q9u[kk];
          cu      = lt ? q9u[kk] : cu;
          q9u[kk] = mn;
        }
      }
    }
    int i = qt * 16 + lane;
#pragma unroll
    for (int k = 0; k < 9; ++k) part[(size_t)(k * SPL + sp) * NN + i] = q9u[k];
  }
}

// ---------- kernel 3: merge SPL sorted partial lists -> nbr, deg ----------
__global__ __launch_bounds__(64) void merge_kernel(const unsigned long long* __restrict__ part,
                                                   int* __restrict__ nbr,
                                                   int* __restrict__ deg) {
  int i = blockIdx.x * 64 + threadIdx.x;
  unsigned long long q9[9];
#pragma unroll
  for (int k = 0; k < 9; ++k) q9[k] = ~0ull;
  for (int s = 0; s < SPL; ++s) {
    for (int k = 0; k < 9; ++k) {
      unsigned long long key = part[(size_t)(k * SPL + s) * NN + i];
      if (key >= q9[8]) break;   // list k-sorted ascending
      unsigned long long cu = key;
#pragma unroll
      for (int m = 0; m < 9; ++m) {
        bool lt = cu < q9[m];
        unsigned long long mn = lt ? cu : q9[m];
        cu    = lt ? q9[m] : cu;
        q9[m] = mn;
      }
    }
  }
  int outi[9];
#pragma unroll
  for (int k = 0; k < 9; ++k) outi[k] = (int)(q9[k] & 0x3FFFull);
  // node 16383 sits alone in "batch 4": top_k over one valid entry + (-inf) ties
  // -> neighbors {16383, 0,1,...,7} (lowest-index tie-break). Matters for deg[0..7].
  if (i == NN - 1) {
    outi[0] = NN - 1;
#pragma unroll
    for (int k = 1; k < 9; ++k) outi[k] = k - 1;
  }
#pragma unroll
  for (int k = 0; k < 9; ++k) {
    nbr[i * 9 + k] = outi[k];
    atomicAdd(&deg[outi[k]], 1);
  }
}

// ---------- kernel 4: tx1 gather + out = relu(xf@W0 + tx1@W1 + b) ----------
__global__ __launch_bounds__(256) void out_kernel(const float* __restrict__ xg,
                                                  const int* __restrict__ nbr,
                                                  const int* __restrict__ deg,
                                                  const float* __restrict__ W0,
                                                  const float* __restrict__ W1,
                                                  const float* __restrict__ bias,
                                                  float* __restrict__ out) {
  __shared__ float w0s[48 * 48], w1s[48 * 48], bsh[48];
  __shared__ __align__(16) float xr[64 * 48];
  __shared__ float tx[64 * 48];
  __shared__ float wd[64][9];
  __shared__ int   jn[64][9];
  __shared__ float din[64];
  int tid = threadIdx.x;
  int r0  = blockIdx.x * 64;

  for (int p = tid; p < 2304; p += 256) { w0s[p] = W0[p]; w1s[p] = W1[p]; }
  if (tid < 48) bsh[tid] = bias[tid];
  if (tid < 64) {
    int d = deg[r0 + tid];
    din[tid] = d > 0 ? rsqrtf((float)d) : 0.0f;
  }
  const float4* xg4 = (const float4*)xg;
  float4* xr4 = (float4*)xr;
  for (int p = tid; p < 768; p += 256) {
    int r = p / 12, q = p - r * 12;
    xr4[r * 12 + q] = xg4[(r0 + r) * 13 + q];
  }
  for (int p = tid; p < 576; p += 256) {
    int r = p / 9, k = p - r * 9;
    int j = nbr[(r0 + r) * 9 + k];
    jn[r][k] = j;
    int d = deg[j];
    wd[r][k] = d > 0 ? rsqrtf((float)d) : 0.0f;
  }
  __syncthreads();

  for (int p = tid; p < 3072; p += 256) {
    int r = p / 48, ch = p - r * 48;
    float s = 0.f;
#pragma unroll
    for (int k = 0; k < 9; ++k) s += wd[r][k] * xg[jn[r][k] * 52 + ch];
    tx[r * 48 + ch] = -din[r] * s;
  }
  __syncthreads();

  for (int p = tid; p < 3072; p += 256) {
    int r = p / 48, o = p - r * 48;
    float acc = bsh[o];
#pragma unroll
    for (int cc = 0; cc < 48; ++cc)
      acc += xr[r * 48 + cc] * w0s[cc * 48 + o] + tx[r * 48 + cc] * w1s[cc * 48 + o];
    out[(r0 + r) * 48 + o] = fmaxf(acc, 0.f);
  }
}

extern "C" void kernel_launch(void* const* d_in, const int* in_sizes, int n_in,
                              void* d_out, int out_size, void* d_ws, size_t ws_size,
                              hipStream_t stream) {
  const float* x  = (const float*)d_in[0];
  const float* W0 = (const float*)d_in[1];
  const float* W1 = (const float*)d_in[2];
  const float* b  = (const float*)d_in[3];
  float* out = (float*)d_out;
  char* ws = (char*)d_ws;
  float*          xg   = (float*)(ws);                       // 3,407,872 B
  unsigned short* xh   = (unsigned short*)(ws + 3407872);    // 2,097,152 B
  unsigned short* xl   = (unsigned short*)(ws + 5505024);    // 2,097,152 B
  float*          sqv  = (float*)(ws + 7602176);             //    65,536 B
  int*            nbr  = (int*)(ws + 7667712);               //   589,824 B
  int*            deg  = (int*)(ws + 8257536);               //    65,536 B
  unsigned long long* part = (unsigned long long*)(ws + 8323072);  // 4,718,592 B

  prep_kernel<<<256, 256, 0, stream>>>(x, xg, xh, xl, sqv, deg);
  knn_kernel<<<1024, 256, 0, stream>>>(xh, xl, sqv, part);
  merge_kernel<<<256, 64, 0, stream>>>(part, nbr, deg);
  out_kernel<<<256, 256, 0, stream>>>(xg, nbr, deg, W0, W1, b, out);
}